// Round 16
// baseline (54.257 us; speedup 1.0000x reference)
//
#include <hip/hip_runtime.h>
#include <hip/hip_bf16.h>
#include <stdint.h>

#define BATCH 16384
#define NCLS 1000
#define NPAD 1024        // 4 N-blocks x 256
#define EMB 768
#define KT 12            // K-steps of 64
#define BM 128
#define BN 256
#define ABYTES 8192      // 128 rows x 64 B
#define BUFB 24576       // A 8K + B 16K
#define GEMM_BLKS 512    // 128 mb x 4 nb, 2 blocks/CU
#define CE_BLKS 4096     // BATCH/4, wave per row

typedef __attribute__((ext_vector_type(4))) float f32x4;
typedef long v2i64 __attribute__((ext_vector_type(2)));

#define GLOAD16(g, l) __builtin_amdgcn_global_load_lds(              \
    (const __attribute__((address_space(1))) unsigned int*)(g),       \
    (__attribute__((address_space(3))) unsigned int*)(l), 16, 0, 0)

__device__ __forceinline__ float d4(float4 v) {
    return v.x*v.x + v.y*v.y + v.z*v.z + v.w*v.w;
}
__device__ __forceinline__ float e4(float4 v) {
    return __expf(v.x) + __expf(v.y) + __expf(v.z) + __expf(v.w);
}
__device__ __forceinline__ unsigned int pk8(float4 v, float s) {
    int p = 0;
    p = __builtin_amdgcn_cvt_pk_fp8_f32(v.x * s, v.y * s, p, false);
    p = __builtin_amdgcn_cvt_pk_fp8_f32(v.z * s, v.w * s, p, true);
    return (unsigned int)p;
}

// ---- prep_ec: emb+cent normalize ONLY. Block-per-row, 192 threads =
// exactly 1 float4/thread (r15-measured ~6 us standalone).
// Blocks 0..16383: emb rows. Blocks 16384..17407: cent rows (pads -> 0). ----
__global__ __launch_bounds__(192) void prep_ec(
    const float* __restrict__ emb, const float* __restrict__ cent,
    unsigned int* __restrict__ en8, unsigned int* __restrict__ cn8)
{
    __shared__ float ssp[3];
    const int b    = blockIdx.x;
    const int tid  = threadIdx.x;
    const int w    = tid >> 6;
    const int lane = tid & 63;

    const bool isC = b >= BATCH;
    const int row  = isC ? b - BATCH : b;
    const bool valid = !isC || row < NCLS;

    const float4* src = isC ? (const float4*)(cent + (size_t)row * EMB)
                            : (const float4*)(emb + (size_t)row * EMB);
    float4 v = (valid) ? src[tid] : make_float4(0.f, 0.f, 0.f, 0.f);

    float ss = d4(v);
    #pragma unroll
    for (int m = 1; m < 64; m <<= 1) ss += __shfl_xor(ss, m, 64);
    if (lane == 0) ssp[w] = ss;
    __syncthreads();
    const float tot = ssp[0] + ssp[1] + ssp[2];
    const float sc = valid ? (1.0f / fmaxf(sqrtf(tot), 1e-8f)) : 0.0f;

    unsigned int* op = (isC ? cn8 : en8) + (size_t)row * (EMB / 4);
    op[tid] = pk8(v, sc);
}

// ---- ce_kernel: STANDALONE wave-per-row CE (r4 shape — the only config
// where this ran fast; no LDS allocation, no atomics, min footprint).
// ce_row[row] = lse(logits_row) - x_t; logits ~N(0,1): no max-shift. ----
__global__ __launch_bounds__(256) void ce_kernel(
    const float* __restrict__ logits, const int* __restrict__ targets,
    float* __restrict__ ce_row)
{
    const int row  = blockIdx.x * 4 + (threadIdx.x >> 6);
    const int lane = threadIdx.x & 63;
    const float* rp = logits + (size_t)row * NCLS;
    const float4* r4 = (const float4*)rp;

    float4 v0 = r4[lane];
    float4 v1 = r4[lane + 64];
    float4 v2 = r4[lane + 128];
    const bool has = lane < 58;
    float4 v3 = has ? r4[lane + 192] : v0;

    float s = e4(v0) + e4(v1) + e4(v2);
    if (has) s += e4(v3);

    #pragma unroll
    for (int m = 1; m < 64; m <<= 1) s += __shfl_xor(s, m, 64);

    if (lane == 0) {
        float xt = rp[targets[row]];
        ce_row[row] = __logf(s) - xt;
    }
}

// ---- GEMM + online stats, STANDALONE (r12 shape, ~9-10 us inferred).
// 512 blocks = 2/CU. BM=128 x BN=256, BK=64, 4 waves (2x2), per-wave
// 64x128 (acc[4][8]). global_load_lds dbuf staging, 0-conflict XOR
// swizzle (r8-verified). Transposed MFMA: D[class][emb]. ----
__global__ __launch_bounds__(256, 2) void gemm_kernel(
    const uint8_t* __restrict__ en8, const uint8_t* __restrict__ cn8,
    const int* __restrict__ targets,
    float* __restrict__ partZ, float* __restrict__ partS2,
    float* __restrict__ et_out)
{
    __shared__ __align__(128) uint8_t lds[2][BUFB];

    const int bid  = blockIdx.x;
    const int tid  = threadIdx.x;
    const int lane = tid & 63;
    const int warp = tid >> 6;

    // XCD-grouped decode: XCD g = bid&7 owns mbs [16g, 16g+16).
    const int g   = bid & 7;
    const int s   = bid >> 3;          // 0..63
    const int mb  = g * 16 + (s >> 2);
    const int nb  = s & 3;
    const int R0  = mb * BM;
    const int Nc0 = nb * BN;
    const int wr  = warp >> 1;         // 0,1: 64-row emb half
    const int wc  = warp & 1;          // 0,1: 128-class half
    const int l15 = lane & 15;
    const int rq  = lane >> 4;

    // Staging: thread covers chunk ci = j*256 + tid; LDS row = j*64+(tid>>2),
    // chunk c = tid&3; source col pre-swizzled (rule #21).
    const int csw  = ((tid & 3) * 16) ^ (((tid >> 3) & 3) << 4);
    const int srow = tid >> 2;
    size_t asrc[2], bsrc[4];
    #pragma unroll
    for (int j = 0; j < 2; ++j) asrc[j] = (size_t)(R0  + j * 64 + srow) * EMB + csw;
    #pragma unroll
    for (int j = 0; j < 4; ++j) bsrc[j] = (size_t)(Nc0 + j * 64 + srow) * EMB + csw;
    const uint8_t* enb = en8;
    const uint8_t* cnb = cn8;

#define STAGE(b, kt) do { const size_t ko = (size_t)(kt) * 64;               \
    _Pragma("unroll") for (int j = 0; j < 2; ++j)                            \
        GLOAD16(enb + asrc[j] + ko, &lds[b][j * 4096 + tid * 16]);           \
    _Pragma("unroll") for (int j = 0; j < 4; ++j)                            \
        GLOAD16(cnb + bsrc[j] + ko, &lds[b][ABYTES + j * 4096 + tid * 16]);  \
} while (0)

    // Fragment read offsets (b128 = kk0|kk1 pair), same XOR family.
    const int cx   = (rq * 16) ^ (((l15 >> 1) & 3) << 4);
    const int aoff = (wr * 64 + l15) * 64 + cx;              // + m*1024
    const int boff = ABYTES + (wc * 128 + l15) * 64 + cx;    // + n*1024

    f32x4 acc[4][8];
    #pragma unroll
    for (int m = 0; m < 4; ++m)
        #pragma unroll
        for (int n = 0; n < 8; ++n) acc[m][n] = (f32x4){0.f, 0.f, 0.f, 0.f};

    STAGE(0, 0);
    __syncthreads();

    for (int kt = 0; kt < KT; ++kt) {
        const int buf = kt & 1;
        if (kt + 1 < KT) STAGE(buf ^ 1, kt + 1);
        const uint8_t* L = &lds[buf][0];
        v2i64 af[4], bf[8];
        #pragma unroll
        for (int m = 0; m < 4; ++m) af[m] = *(const v2i64*)(L + aoff + m * 1024);
        #pragma unroll
        for (int n = 0; n < 8; ++n) bf[n] = *(const v2i64*)(L + boff + n * 1024);
        #pragma unroll
        for (int kk = 0; kk < 2; ++kk)
            #pragma unroll
            for (int m = 0; m < 4; ++m)
                #pragma unroll
                for (int n = 0; n < 8; ++n)
                    acc[m][n] = __builtin_amdgcn_mfma_f32_16x16x32_fp8_fp8(
                        bf[n][kk], af[m][kk], acc[m][n], 0, 0, 0);
        __syncthreads();   // drains next-tile DMA + guards overwrite
    }
#undef STAGE

    // ---- epilogue: acc[m][n][r] = sim[class = Nc0+wc*128+n*16+rq*4+r]
    //                                 [emb row = R0+wr*64+m*16+l15]
    const int plane = nb * 2 + wc;    // 128-class slab, 0..7
    #pragma unroll
    for (int m = 0; m < 4; ++m) {
        const int row = R0 + wr * 64 + m * 16 + l15;
        const int t   = targets[row];
        float z = 0.f, s2 = 0.f;
        #pragma unroll
        for (int n = 0; n < 8; ++n) {
            const int cb = Nc0 + wc * 128 + n * 16 + rq * 4;
            #pragma unroll
            for (int r = 0; r < 4; ++r) {
                const bool valid = (cb + r) < NCLS;
                float e = valid ? __expf(acc[m][n][r]) : 0.f;
                z += e; s2 += e * e;
                if (cb + r == t) et_out[row] = e;   // unique owner grid-wide
            }
        }
        z  += __shfl_xor(z, 16, 64);  z  += __shfl_xor(z, 32, 64);
        s2 += __shfl_xor(s2, 16, 64); s2 += __shfl_xor(s2, 32, 64);
        if (rq == 0) {
            partZ [(size_t)plane * BATCH + row] = z;
            partS2[(size_t)plane * BATCH + row] = s2;
        }
    }
}

// ---- finalize stage 1: per-row loss terms -> 64 block partials ----
__global__ __launch_bounds__(256) void finalize1(
    const float* __restrict__ partZ, const float* __restrict__ partS2,
    const float* __restrict__ et_out, const float* __restrict__ ce_row,
    const float* __restrict__ u, float* __restrict__ fpart)
{
    __shared__ float red[4];
    const int row  = blockIdx.x * 256 + threadIdx.x;
    const int lane = threadIdx.x & 63;
    float z = 0.f, s2 = 0.f;
    #pragma unroll
    for (int i = 0; i < 8; ++i) {
        z  += partZ [(size_t)i * BATCH + row];
        s2 += partS2[(size_t)i * BATCH + row];
    }
    float et = et_out[row];
    float invz = 1.0f / z;
    float pt = et * invz;
    float c = (s2 * invz * invz - 2.0f * pt + 1.0f) * (1.0f / ((float)BATCH * (float)NCLS))
            + (1.0f - pt) * u[0] * (1.0f / (float)BATCH)
            + ce_row[row] * (1.0f / (float)BATCH);
    #pragma unroll
    for (int m = 1; m < 64; m <<= 1) c += __shfl_xor(c, m, 64);
    if (lane == 0) red[threadIdx.x >> 6] = c;
    __syncthreads();
    if (threadIdx.x == 0) fpart[blockIdx.x] = red[0] + red[1] + red[2] + red[3];
}

// ---- finalize stage 2: 64 partials -> scalar (plain store, no atomics) ----
__global__ __launch_bounds__(64) void finalize2(
    const float* __restrict__ fpart, float* __restrict__ out)
{
    const int lane = threadIdx.x;
    float s = fpart[lane];
    #pragma unroll
    for (int m = 1; m < 64; m <<= 1) s += __shfl_xor(s, m, 64);
    if (lane == 0) out[0] = s;
}

extern "C" void kernel_launch(void* const* d_in, const int* in_sizes, int n_in,
                              void* d_out, int out_size, void* d_ws, size_t ws_size,
                              hipStream_t stream) {
    const float* emb       = (const float*)d_in[0];
    const float* logits    = (const float*)d_in[1];
    const int*   targets   = (const int*)d_in[2];
    const float* centroids = (const float*)d_in[3];
    const float* u         = (const float*)d_in[4];
    float* out = (float*)d_out;

    uint8_t* en8  = (uint8_t*)d_ws;                         // 16384*768 = 12,582,912
    uint8_t* cn8  = en8 + (size_t)BATCH * EMB;              //  1024*768 =    786,432
    float* partZ  = (float*)(cn8 + (size_t)NPAD * EMB);     //  8*16384*4 =   524,288
    float* partS2 = partZ + 8 * BATCH;                      //               524,288
    float* et_out = partS2 + 8 * BATCH;                     //                65,536
    float* ce_row = et_out + BATCH;                         //                65,536
    float* fpart  = ce_row + BATCH;                         //                   256

    prep_ec<<<BATCH + NPAD, 192, 0, stream>>>(emb, centroids,
                                              (unsigned int*)en8, (unsigned int*)cn8);
    ce_kernel<<<CE_BLKS, 256, 0, stream>>>(logits, targets, ce_row);
    gemm_kernel<<<GEMM_BLKS, 256, 0, stream>>>(en8, cn8, targets, partZ, partS2, et_out);
    finalize1<<<BATCH / 256, 256, 0, stream>>>(partZ, partS2, et_out, ce_row, u, fpart);
    finalize2<<<1, 64, 0, stream>>>(fpart, out);
}

// Round 18
// 52.481 us; speedup vs baseline: 1.0338x; 1.0338x over previous
//
#include <hip/hip_runtime.h>
#include <hip/hip_bf16.h>
#include <stdint.h>

#define BATCH 16384
#define NCLS 1000
#define NPAD 1024        // 4 N-blocks x 256
#define EMB 768
#define KT 12            // K-steps of 64
#define BM 128
#define BN 256
#define ABYTES 8192      // 128 rows x 64 B
#define BUFB 24576       // A 8K + B 16K
#define GEMM_BLKS 512    // 128 mb x 4 nb, 2 blocks/CU
#define PREP_BATCH 512   // 32 batch rows per block
#define PREP_CENT 32     // 32 cent rows per block

typedef __attribute__((ext_vector_type(4))) float f32x4;
typedef long v2i64 __attribute__((ext_vector_type(2)));

#define GLOAD16(g, l) __builtin_amdgcn_global_load_lds(              \
    (const __attribute__((address_space(1))) unsigned int*)(g),       \
    (__attribute__((address_space(3))) unsigned int*)(l), 16, 0, 0)

// Asm loads: outputs are forced live from issue to use — regalloc cannot
// sink/serialize them (r10/r11/r13 failure). r17 lesson: keep the live set
// small (<=14 float4) and use ONLY vmcnt(0) waits (counted waits break when
// the compiler adds its own vmem ops).
#define GL4(d, a) asm volatile("global_load_dwordx4 %0, %1, off" : "=v"(d) : "v"(a) : "memory")
#define WAIT0() do { asm volatile("s_waitcnt vmcnt(0)" ::: "memory"); \
                     __builtin_amdgcn_sched_barrier(0); } while (0)

__device__ __forceinline__ float d4(float4 v) {
    return v.x*v.x + v.y*v.y + v.z*v.z + v.w*v.w;
}
__device__ __forceinline__ float e4(float4 v) {
    return __expf(v.x) + __expf(v.y) + __expf(v.z) + __expf(v.w);
}
__device__ __forceinline__ unsigned int pk8(float4 v, float s) {
    int p = 0;
    p = __builtin_amdgcn_cvt_pk_fp8_f32(v.x * s, v.y * s, p, false);
    p = __builtin_amdgcn_cvt_pk_fp8_f32(v.z * s, v.w * s, p, true);
    return (unsigned int)p;
}

// ---- prep_asm: emb-norm + CE with asm-load MLP.
// Blocks 0..511: 32 batch rows (8 per wave, processed in 4 chunks of 2).
// Per chunk: 14 asm global_load_dwordx4 issued back-to-back (deep MLP),
// vmcnt(0), then reduce/pack/store. Target logits preloaded+pinned BEFORE
// the asm region so no compiler loads mix with asm loads.
// Blocks 512..543: 32 centroid rows (pads -> zero scale). ----
__global__ __launch_bounds__(256) void prep_asm(
    const float* __restrict__ emb, const float* __restrict__ cent,
    const float* __restrict__ logits, const int* __restrict__ targets,
    unsigned int* __restrict__ en8, unsigned int* __restrict__ cn8,
    float* __restrict__ ce_row)
{
    const int b    = blockIdx.x;
    const int w    = threadIdx.x >> 6;
    const int lane = threadIdx.x & 63;

    if (b < PREP_BATCH) {
        const int rw = b * 32 + w * 8;
        const bool has = lane < 58;   // logits 4th chunk valid lanes

        // Preload + pin all 8 target logits BEFORE the asm region.
        float xt[8];
        #pragma unroll
        for (int j = 0; j < 8; ++j)
            xt[j] = logits[(size_t)(rw + j) * NCLS + targets[rw + j]];
        #pragma unroll
        for (int j = 0; j < 8; ++j) asm volatile("" : "+v"(xt[j]));

        #pragma unroll
        for (int p = 0; p < 4; ++p) {
            const int r = rw + 2 * p;
            const float* e0p = emb + (size_t)r * EMB;
            const float* e1p = e0p + EMB;
            const float* l0p = logits + (size_t)r * NCLS;
            const float* l1p = l0p + NCLS;

            float4 e0, e1, e2, e3, e4v, e5, l0, l1, l2, l3, l4, l5, l6, l7;
            // ISSUE: 14 loads back-to-back, nothing between.
            GL4(e0, e0p + lane * 4);        GL4(e1, e0p + lane * 4 + 256);
            GL4(e2, e0p + lane * 4 + 512);
            GL4(e3, e1p + lane * 4);        GL4(e4v, e1p + lane * 4 + 256);
            GL4(e5, e1p + lane * 4 + 512);
            GL4(l0, l0p + lane * 4);        GL4(l1, l0p + lane * 4 + 256);
            GL4(l2, l0p + lane * 4 + 512);  GL4(l3, has ? (l0p + lane * 4 + 768) : l0p);
            GL4(l4, l1p + lane * 4);        GL4(l5, l1p + lane * 4 + 256);
            GL4(l6, l1p + lane * 4 + 512);  GL4(l7, has ? (l1p + lane * 4 + 768) : l1p);
            WAIT0();

            // COMPUTE rows r, r+1
            float ss0 = d4(e0) + d4(e1) + d4(e2);
            float ss1 = d4(e3) + d4(e4v) + d4(e5);
            float es0 = e4(l0) + e4(l1) + e4(l2);
            float es1 = e4(l4) + e4(l5) + e4(l6);
            if (has) { es0 += e4(l3); es1 += e4(l7); }
            #pragma unroll
            for (int m = 1; m < 64; m <<= 1) {
                ss0 += __shfl_xor(ss0, m, 64); ss1 += __shfl_xor(ss1, m, 64);
                es0 += __shfl_xor(es0, m, 64); es1 += __shfl_xor(es1, m, 64);
            }
            const float sc0 = 1.0f / fmaxf(sqrtf(ss0), 1e-8f);
            const float sc1 = 1.0f / fmaxf(sqrtf(ss1), 1e-8f);
            unsigned int* o = en8 + (size_t)r * 192 + lane;
            o[0]   = pk8(e0, sc0); o[64]  = pk8(e1, sc0); o[128] = pk8(e2, sc0);
            o[192] = pk8(e3, sc1); o[256] = pk8(e4v, sc1); o[320] = pk8(e5, sc1);
            if (lane == 0) {
                ce_row[r]     = __logf(es0) - xt[2 * p];
                ce_row[r + 1] = __logf(es1) - xt[2 * p + 1];
            }
        }
        return;
    }

    // ---- centroid rows: 32 per block (3 MB total, simple path) ----
    const int c0 = (b - PREP_BATCH) * 32 + w * 8;
    for (int j = 0; j < 8; ++j) {
        const int row = c0 + j;
        const bool hv = row < NCLS;
        const float* cr = cent + (size_t)(hv ? row : NCLS - 1) * EMB;
        float4 v0 = *((const float4*)cr + lane);
        float4 v1 = *((const float4*)cr + lane + 64);
        float4 v2 = *((const float4*)cr + lane + 128);
        float ss = d4(v0) + d4(v1) + d4(v2);
        #pragma unroll
        for (int m = 1; m < 64; m <<= 1) ss += __shfl_xor(ss, m, 64);
        const float sc = hv ? (1.0f / fmaxf(sqrtf(ss), 1e-8f)) : 0.0f;
        unsigned int* op = cn8 + (size_t)row * 192 + lane;
        op[0] = pk8(v0, sc); op[64] = pk8(v1, sc); op[128] = pk8(v2, sc);
    }
}

// ---- GEMM + online stats (r12 shape, known good). 512 blocks = 2/CU.
// BM=128 x BN=256, BK=64, 4 waves (2x2), per-wave 64x128 (acc[4][8]).
// global_load_lds dbuf staging, 0-conflict XOR swizzle. Transposed MFMA. ----
__global__ __launch_bounds__(256, 2) void gemm_kernel(
    const uint8_t* __restrict__ en8, const uint8_t* __restrict__ cn8,
    const int* __restrict__ targets,
    float* __restrict__ partZ, float* __restrict__ partS2,
    float* __restrict__ et_out)
{
    __shared__ __align__(128) uint8_t lds[2][BUFB];

    const int bid  = blockIdx.x;
    const int tid  = threadIdx.x;
    const int lane = tid & 63;
    const int warp = tid >> 6;

    const int g   = bid & 7;
    const int s   = bid >> 3;
    const int mb  = g * 16 + (s >> 2);
    const int nb  = s & 3;
    const int R0  = mb * BM;
    const int Nc0 = nb * BN;
    const int wr  = warp >> 1;
    const int wc  = warp & 1;
    const int l15 = lane & 15;
    const int rq  = lane >> 4;

    const int csw  = ((tid & 3) * 16) ^ (((tid >> 3) & 3) << 4);
    const int srow = tid >> 2;
    size_t asrc[2], bsrc[4];
    #pragma unroll
    for (int j = 0; j < 2; ++j) asrc[j] = (size_t)(R0  + j * 64 + srow) * EMB + csw;
    #pragma unroll
    for (int j = 0; j < 4; ++j) bsrc[j] = (size_t)(Nc0 + j * 64 + srow) * EMB + csw;
    const uint8_t* enb = en8;
    const uint8_t* cnb = cn8;

#define STAGE(b, kt) do { const size_t ko = (size_t)(kt) * 64;               \
    _Pragma("unroll") for (int j = 0; j < 2; ++j)                            \
        GLOAD16(enb + asrc[j] + ko, &lds[b][j * 4096 + tid * 16]);           \
    _Pragma("unroll") for (int j = 0; j < 4; ++j)                            \
        GLOAD16(cnb + bsrc[j] + ko, &lds[b][ABYTES + j * 4096 + tid * 16]);  \
} while (0)

    const int cx   = (rq * 16) ^ (((l15 >> 1) & 3) << 4);
    const int aoff = (wr * 64 + l15) * 64 + cx;
    const int boff = ABYTES + (wc * 128 + l15) * 64 + cx;

    f32x4 acc[4][8];
    #pragma unroll
    for (int m = 0; m < 4; ++m)
        #pragma unroll
        for (int n = 0; n < 8; ++n) acc[m][n] = (f32x4){0.f, 0.f, 0.f, 0.f};

    STAGE(0, 0);
    __syncthreads();

    for (int kt = 0; kt < KT; ++kt) {
        const int buf = kt & 1;
        if (kt + 1 < KT) STAGE(buf ^ 1, kt + 1);
        const uint8_t* L = &lds[buf][0];
        v2i64 af[4], bf[8];
        #pragma unroll
        for (int m = 0; m < 4; ++m) af[m] = *(const v2i64*)(L + aoff + m * 1024);
        #pragma unroll
        for (int n = 0; n < 8; ++n) bf[n] = *(const v2i64*)(L + boff + n * 1024);
        #pragma unroll
        for (int kk = 0; kk < 2; ++kk)
            #pragma unroll
            for (int m = 0; m < 4; ++m)
                #pragma unroll
                for (int n = 0; n < 8; ++n)
                    acc[m][n] = __builtin_amdgcn_mfma_f32_16x16x32_fp8_fp8(
                        bf[n][kk], af[m][kk], acc[m][n], 0, 0, 0);
        __syncthreads();
    }
#undef STAGE

    const int plane = nb * 2 + wc;
    #pragma unroll
    for (int m = 0; m < 4; ++m) {
        const int row = R0 + wr * 64 + m * 16 + l15;
        const int t   = targets[row];
        float z = 0.f, s2 = 0.f;
        #pragma unroll
        for (int n = 0; n < 8; ++n) {
            const int cb = Nc0 + wc * 128 + n * 16 + rq * 4;
            #pragma unroll
            for (int r = 0; r < 4; ++r) {
                const bool valid = (cb + r) < NCLS;
                float e = valid ? __expf(acc[m][n][r]) : 0.f;
                z += e; s2 += e * e;
                if (cb + r == t) et_out[row] = e;
            }
        }
        z  += __shfl_xor(z, 16, 64);  z  += __shfl_xor(z, 32, 64);
        s2 += __shfl_xor(s2, 16, 64); s2 += __shfl_xor(s2, 32, 64);
        if (rq == 0) {
            partZ [(size_t)plane * BATCH + row] = z;
            partS2[(size_t)plane * BATCH + row] = s2;
        }
    }
}

// ---- finalize stage 1: per-row loss terms -> 64 block partials ----
__global__ __launch_bounds__(256) void finalize1(
    const float* __restrict__ partZ, const float* __restrict__ partS2,
    const float* __restrict__ et_out, const float* __restrict__ ce_row,
    const float* __restrict__ u, float* __restrict__ fpart)
{
    __shared__ float red[4];
    const int row  = blockIdx.x * 256 + threadIdx.x;
    const int lane = threadIdx.x & 63;
    float z = 0.f, s2 = 0.f;
    #pragma unroll
    for (int i = 0; i < 8; ++i) {
        z  += partZ [(size_t)i * BATCH + row];
        s2 += partS2[(size_t)i * BATCH + row];
    }
    float et = et_out[row];
    float invz = 1.0f / z;
    float pt = et * invz;
    float c = (s2 * invz * invz - 2.0f * pt + 1.0f) * (1.0f / ((float)BATCH * (float)NCLS))
            + (1.0f - pt) * u[0] * (1.0f / (float)BATCH)
            + ce_row[row] * (1.0f / (float)BATCH);
    #pragma unroll
    for (int m = 1; m < 64; m <<= 1) c += __shfl_xor(c, m, 64);
    if (lane == 0) red[threadIdx.x >> 6] = c;
    __syncthreads();
    if (threadIdx.x == 0) fpart[blockIdx.x] = red[0] + red[1] + red[2] + red[3];
}

// ---- finalize stage 2: 64 partials -> scalar ----
__global__ __launch_bounds__(64) void finalize2(
    const float* __restrict__ fpart, float* __restrict__ out)
{
    const int lane = threadIdx.x;
    float s = fpart[lane];
    #pragma unroll
    for (int m = 1; m < 64; m <<= 1) s += __shfl_xor(s, m, 64);
    if (lane == 0) out[0] = s;
}

extern "C" void kernel_launch(void* const* d_in, const int* in_sizes, int n_in,
                              void* d_out, int out_size, void* d_ws, size_t ws_size,
                              hipStream_t stream) {
    const float* emb       = (const float*)d_in[0];
    const float* logits    = (const float*)d_in[1];
    const int*   targets   = (const int*)d_in[2];
    const float* centroids = (const float*)d_in[3];
    const float* u         = (const float*)d_in[4];
    float* out = (float*)d_out;

    uint8_t* en8  = (uint8_t*)d_ws;                         // 16384*768 = 12,582,912
    uint8_t* cn8  = en8 + (size_t)BATCH * EMB;              //  1024*768 =    786,432
    float* partZ  = (float*)(cn8 + (size_t)NPAD * EMB);     //  8*16384*4 =   524,288
    float* partS2 = partZ + 8 * BATCH;                      //               524,288
    float* et_out = partS2 + 8 * BATCH;                     //                65,536
    float* ce_row = et_out + BATCH;                         //                65,536
    float* fpart  = ce_row + BATCH;                         //                   256

    prep_asm<<<PREP_BATCH + PREP_CENT, 256, 0, stream>>>(
        emb, centroids, logits, targets,
        (unsigned int*)en8, (unsigned int*)cn8, ce_row);
    gemm_kernel<<<GEMM_BLKS, 256, 0, stream>>>(en8, cn8, targets, partZ, partS2, et_out);
    finalize1<<<BATCH / 256, 256, 0, stream>>>(partZ, partS2, et_out, ce_row, u, fpart);
    finalize2<<<1, 64, 0, stream>>>(fpart, out);
}